// Round 8
// baseline (263.940 us; speedup 1.0000x reference)
//
#include <hip/hip_runtime.h>
#include <hip/hip_bf16.h>
#include <math.h>

#define BATCH 2
#define CC    256
#define NN    4096
#define KK    409          // max(1, int(0.1*4096))
#define KCAT  768          // split-fp16 concat K
#define SCALE 0.0625f      // 1/sqrt(256)
#define PSTRIDE 8192       // P row stride in halfs (P aliases S rows)

typedef _Float16 half8 __attribute__((ext_vector_type(8)));
typedef float    floatx4 __attribute__((ext_vector_type(4)));

// async global->LDS, 16B per lane; LDS dest = wave-uniform base + lane*16
typedef __attribute__((address_space(3))) unsigned       lds_u32;
typedef __attribute__((address_space(1))) const unsigned glb_u32;
__device__ __forceinline__ void gload16(const void* g, void* l) {
    __builtin_amdgcn_global_load_lds((glb_u32*)g, (lds_u32*)l, 16, 0, 0);
}

// ---------- helpers: order-preserving float<->uint key ----------
__device__ __forceinline__ unsigned fkey(float f) {
    unsigned u = __float_as_uint(f);
    return (u & 0x80000000u) ? ~u : (u | 0x80000000u);
}
__device__ __forceinline__ float keyToF(unsigned k) {
    unsigned u = (k & 0x80000000u) ? (k ^ 0x80000000u) : ~k;
    return __uint_as_float(u);
}

// ---------- kernel 1: x[b][c][n] f32 -> xcat[b*N+n][768] = [hi, lo, hi] ----------
__global__ __launch_bounds__(256) void xpose_kernel(
        const float* __restrict__ x, _Float16* __restrict__ xcat) {
    __shared__ float xs[64][68];
    const int t  = threadIdx.x;
    const int n0 = blockIdx.x * 64;
    const int c0 = blockIdx.y * 64;
    const int b  = blockIdx.z;

    {
        const int ci = t >> 2;
        const int j  = (t & 3) * 16;
        const float* xp = x + ((size_t)((b << 8) + c0 + ci)) * NN + n0 + j;
        float4 a0 = ((const float4*)xp)[0];
        float4 a1 = ((const float4*)xp)[1];
        float4 a2 = ((const float4*)xp)[2];
        float4 a3 = ((const float4*)xp)[3];
        *(float4*)&xs[ci][j]      = a0;
        *(float4*)&xs[ci][j + 4]  = a1;
        *(float4*)&xs[ci][j + 8]  = a2;
        *(float4*)&xs[ci][j + 12] = a3;
    }
    __syncthreads();

    const int n = t >> 2;
    const int g0 = t & 3;
    _Float16* xr = xcat + ((size_t)(b * NN + n0 + n)) * KCAT + c0;
#pragma unroll
    for (int gg = 0; gg < 2; gg++) {
        int g = g0 + gg * 4;
        half8 hi, lo;
#pragma unroll
        for (int k = 0; k < 8; k++) {
            float v = xs[g * 8 + k][n];
            _Float16 h = (_Float16)v;
            hi[k] = h;
            lo[k] = (_Float16)(v - (float)h);
        }
        *(half8*)(xr + g * 8)       = hi;
        *(half8*)(xr + 256 + g * 8) = lo;
        *(half8*)(xr + 512 + g * 8) = hi;
    }
}

// ---------- kernel 2: W[o][c] -> Wcat[mat][o][768] = [whi, whi, wlo] ----------
__global__ void wcat_kernel(const float* __restrict__ Wq,
                            const float* __restrict__ Wk,
                            const float* __restrict__ Wv,
                            _Float16* __restrict__ Wcat) {
    int mat = blockIdx.x >> 8;
    int o   = blockIdx.x & 255;
    int c   = threadIdx.x;
    const float* W = (mat == 0) ? Wq : (mat == 1) ? Wk : Wv;
    float v = W[o * 256 + c];
    _Float16 hi = (_Float16)v;
    _Float16 lo = (_Float16)(v - (float)hi);
    _Float16* wr = Wcat + ((size_t)(mat * 256 + o)) * KCAT;
    wr[c] = hi; wr[256 + c] = hi; wr[512 + c] = lo;
}

// ---------- kernel 3: projections via MFMA, 128x128 tile, K=768 ----------
__global__ __launch_bounds__(256) void proj_gemm(
        const _Float16* __restrict__ xcat, const _Float16* __restrict__ Wcat,
        const float* __restrict__ bq, const float* __restrict__ bk,
        const float* __restrict__ bv,
        _Float16* __restrict__ Qcat, _Float16* __restrict__ Kcat,
        _Float16* __restrict__ Vt) {
    __shared__ _Float16 As[128][72];
    __shared__ _Float16 Bs[128][72];

    const int t    = threadIdx.x;
    const int wave = t >> 6;
    const int l    = t & 63;
    const int wr   = wave >> 1;
    const int wc   = wave & 1;
    const int mat  = blockIdx.z;

    int bym, bxn;
    if (mat < 2) { bym = blockIdx.x >> 1; bxn = blockIdx.x & 1; }
    else         { bym = blockIdx.x & 1;  bxn = blockIdx.x >> 1; }

    const int r = t >> 1;
    const int h = t & 1;

    const _Float16* Abase;
    const _Float16* Bbase;
    if (mat < 2) {
        Abase = xcat + ((size_t)(bym * 128 + r)) * KCAT + h * 32;
        Bbase = Wcat + ((size_t)(mat * 256 + bxn * 128 + r)) * KCAT + h * 32;
    } else {
        Abase = Wcat + ((size_t)(512 + bym * 128 + r)) * KCAT + h * 32;
        Bbase = xcat + ((size_t)(bxn * 128 + r)) * KCAT + h * 32;
    }

    floatx4 acc[4][4];
#pragma unroll
    for (int i = 0; i < 4; i++)
#pragma unroll
        for (int j = 0; j < 4; j++) acc[i][j] = (floatx4)0.0f;

    const int rowA = l & 15;
    const int koff = (l >> 4) * 8;

    for (int kc = 0; kc < KCAT; kc += 64) {
        const uint4* ap = (const uint4*)(Abase + kc);
        const uint4* bp = (const uint4*)(Bbase + kc);
        uint4 a0 = ap[0], a1 = ap[1], a2 = ap[2], a3 = ap[3];
        uint4 b0 = bp[0], b1 = bp[1], b2 = bp[2], b3 = bp[3];
        *(uint4*)&As[r][h * 32]      = a0;
        *(uint4*)&As[r][h * 32 + 8]  = a1;
        *(uint4*)&As[r][h * 32 + 16] = a2;
        *(uint4*)&As[r][h * 32 + 24] = a3;
        *(uint4*)&Bs[r][h * 32]      = b0;
        *(uint4*)&Bs[r][h * 32 + 8]  = b1;
        *(uint4*)&Bs[r][h * 32 + 16] = b2;
        *(uint4*)&Bs[r][h * 32 + 24] = b3;
        __syncthreads();
#pragma unroll
        for (int ks = 0; ks < 64; ks += 32) {
            half8 af[4], bf[4];
#pragma unroll
            for (int mi = 0; mi < 4; mi++)
                af[mi] = *(const half8*)&As[wr * 64 + mi * 16 + rowA][ks + koff];
#pragma unroll
            for (int ni = 0; ni < 4; ni++)
                bf[ni] = *(const half8*)&Bs[wc * 64 + ni * 16 + rowA][ks + koff];
#pragma unroll
            for (int mi = 0; mi < 4; mi++)
#pragma unroll
                for (int ni = 0; ni < 4; ni++)
                    acc[mi][ni] = __builtin_amdgcn_mfma_f32_16x16x32_f16(
                        af[mi], bf[ni], acc[mi][ni], 0, 0, 0);
        }
        __syncthreads();
    }

    if (mat < 2) {
        const float* bias = (mat == 0) ? bq : bk;
        _Float16* Out = (mat == 0) ? Qcat : Kcat;
#pragma unroll
        for (int ni = 0; ni < 4; ni++) {
            int ch = bxn * 128 + wc * 64 + ni * 16 + (l & 15);
            float bb = bias[ch];
#pragma unroll
            for (int mi = 0; mi < 4; mi++)
#pragma unroll
                for (int rg = 0; rg < 4; rg++) {
                    int token = bym * 128 + wr * 64 + mi * 16 + (l >> 4) * 4 + rg;
                    float v = acc[mi][ni][rg] + bb;
                    _Float16 hi = (_Float16)v;
                    _Float16 lo = (_Float16)(v - (float)hi);
                    _Float16* p = Out + (size_t)token * KCAT + ch;
                    if (mat == 0) { p[0] = hi; p[256] = lo; p[512] = hi; }
                    else          { p[0] = hi; p[256] = hi; p[512] = lo; }
                }
        }
    } else {
#pragma unroll
        for (int mi = 0; mi < 4; mi++)
#pragma unroll
            for (int rg = 0; rg < 4; rg++) {
                int ch = bym * 128 + wr * 64 + mi * 16 + (l >> 4) * 4 + rg;
                float bb = bv[ch];
#pragma unroll
                for (int ni = 0; ni < 4; ni++) {
                    int col = bxn * 128 + wc * 64 + ni * 16 + (l & 15);
                    int b = col >> 12, n = col & 4095;
                    Vt[((size_t)((b << 8) + ch)) * NN + n] =
                        (_Float16)(acc[mi][ni][rg] + bb);
                }
            }
    }
}

// ---------- kernel 4: S = (Qcat @ Kcat^T) * SCALE via MFMA f16 ----------
// 256x256 block tile (4x reuse vs 128-tile: LLC-BW-bound), 512 thr = 8 waves
// (4x2), wave tile 64x128. Async global_load_lds staging w/ XOR granule
// swizzle: LDS granule (row,g) holds global granule g^(row&7); reads 2-way.
__global__ __launch_bounds__(512, 2) void score_gemm(
        const _Float16* __restrict__ Qcat, const _Float16* __restrict__ Kcat,
        float* __restrict__ S) {
    __shared__ _Float16 As[256][64];
    __shared__ _Float16 Bs[256][64];

    const int t    = threadIdx.x;
    const int wave = t >> 6;             // 0..7
    const int l    = t & 63;
    const int wr   = wave >> 1;          // 0..3 (M, 64 rows)
    const int wc   = wave & 1;           // 0..1 (N, 128 cols)
    const int bxn  = blockIdx.x;         // 16
    const int bym  = blockIdx.y;         // 16
    const int b    = blockIdx.z;

    // staging: 32 A-segments + 32 B-segments of 8 rows; wave handles 4 each
    const int lr = l >> 3;               // row within segment 0..7
    const int gg = (l & 7) ^ lr;         // swizzled source granule

    const _Float16* At = Qcat + ((size_t)((b << 12) + bym * 256)) * KCAT;
    const _Float16* Bt = Kcat + ((size_t)((b << 12) + bxn * 256)) * KCAT;
    const size_t lane_off = (size_t)lr * KCAT + gg * 8;

    floatx4 acc[4][8];
#pragma unroll
    for (int i = 0; i < 4; i++)
#pragma unroll
        for (int j = 0; j < 8; j++) acc[i][j] = (floatx4)0.0f;

    const int rowA = l & 15;
    const int sg0  = (l >> 4) ^ (l & 7);   // swizzled read granule, ks=0
    const int sg1  = sg0 ^ 4;              // ks=32

    for (int kc = 0; kc < KCAT; kc += 64) {
#pragma unroll
        for (int s = 0; s < 4; s++) {
            const int seg = wave * 4 + s;
            gload16(At + (size_t)seg * 8 * KCAT + lane_off + kc, &As[seg * 8][0]);
            gload16(Bt + (size_t)seg * 8 * KCAT + lane_off + kc, &Bs[seg * 8][0]);
        }
        __syncthreads();
#pragma unroll
        for (int ks = 0; ks < 2; ks++) {
            const int sg = ks ? sg1 : sg0;
            half8 af[4], bf[8];
#pragma unroll
            for (int mi = 0; mi < 4; mi++)
                af[mi] = *(const half8*)&As[wr * 64 + mi * 16 + rowA][sg * 8];
#pragma unroll
            for (int ni = 0; ni < 8; ni++)
                bf[ni] = *(const half8*)&Bs[wc * 128 + ni * 16 + rowA][sg * 8];
#pragma unroll
            for (int mi = 0; mi < 4; mi++)
#pragma unroll
                for (int ni = 0; ni < 8; ni++)
                    acc[mi][ni] = __builtin_amdgcn_mfma_f32_16x16x32_f16(
                        af[mi], bf[ni], acc[mi][ni], 0, 0, 0);
        }
        __syncthreads();
    }

    float* Sb = S + ((size_t)b << 24);
#pragma unroll
    for (int mi = 0; mi < 4; mi++)
#pragma unroll
        for (int ni = 0; ni < 8; ni++) {
            int col = bxn * 256 + wc * 128 + ni * 16 + (l & 15);
#pragma unroll
            for (int rg = 0; rg < 4; rg++) {
                int row = bym * 256 + wr * 64 + mi * 16 + (l >> 4) * 4 + rg;
                Sb[((size_t)row << 12) + col] = acc[mi][ni][rg] * SCALE;
            }
        }
}

// ---------- kernel 5: per-row exact top-k + softmax -> dense fp16 P row ----------
__global__ __launch_bounds__(256) void select_scatter(
        const float* __restrict__ S, _Float16* __restrict__ P) {
    __shared__ unsigned hist[256];
    __shared__ unsigned scan[256];
    __shared__ unsigned candKey[NN];     // worst case: all in one bin
    __shared__ unsigned wred[4];
    __shared__ float    fmn[4], fmx[4], wsum[4];
    __shared__ unsigned sh_d, sh_cntgt;
    __shared__ int      sh_ncand;

    const int t = threadIdx.x;
    const int l = t & 63;
    const int w = t >> 6;

    float    val[16];
    unsigned ukey[16];
    {
        const float*  Srow = S + ((size_t)blockIdx.x << 12);
        const float4* sp   = (const float4*)(Srow + t * 16);
#pragma unroll
        for (int jj = 0; jj < 4; jj++) {
            float4 v = sp[jj];
            val[jj * 4 + 0] = v.x; val[jj * 4 + 1] = v.y;
            val[jj * 4 + 2] = v.z; val[jj * 4 + 3] = v.w;
        }
#pragma unroll
        for (int j = 0; j < 16; j++) ukey[j] = fkey(val[j]);
    }

    // row min/max via wave reduce
    float lmin = val[0], lmax = val[0];
#pragma unroll
    for (int j = 1; j < 16; j++) {
        lmin = fminf(lmin, val[j]); lmax = fmaxf(lmax, val[j]);
    }
#pragma unroll
    for (int off = 32; off > 0; off >>= 1) {
        float a = __shfl_down(lmin, off);
        float b = __shfl_down(lmax, off);
        if (l + off < 64) { lmin = fminf(lmin, a); lmax = fmaxf(lmax, b); }
    }
    if (l == 0) { fmn[w] = lmin; fmx[w] = lmax; }

    hist[t] = 0u;
    if (t == 0) sh_ncand = 0;
    __syncthreads();
    const float fmin = fminf(fminf(fmn[0], fmn[1]), fminf(fmn[2], fmn[3]));
    const float fmax = fmaxf(fmaxf(fmx[0], fmx[1]), fmaxf(fmx[2], fmx[3]));
    const float range = fmax - fmin;
    const float bscale = (range > 1e-20f) ? 255.0f / range : 0.0f;

    auto binOf = [&](float v) -> int {
        int bin = (int)((v - fmin) * bscale);
        return bin < 0 ? 0 : (bin > 255 ? 255 : bin);
    };

    // ---- level 1: linear histogram ----
#pragma unroll
    for (int j = 0; j < 16; j++) atomicAdd(&hist[binOf(val[j])], 1u);
    __syncthreads();

    int rem = KK;

    auto find_digit = [&](int remv) {
        unsigned v = hist[t];
#pragma unroll
        for (int off = 1; off < 64; off <<= 1) {
            unsigned o = __shfl_down(v, off);
            if (l + off < 64) v += o;
        }
        if (l == 0) wred[w] = v;
        __syncthreads();
        unsigned add = 0u;
#pragma unroll
        for (int w2 = 0; w2 < 4; w2++) if (w2 > w) add += wred[w2];
        scan[t] = v + add;
        __syncthreads();
        unsigned sufd  = scan[t];
        unsigned sufd1 = (t < 255) ? scan[t + 1] : 0u;
        if (sufd >= (unsigned)remv && sufd1 < (unsigned)remv) {
            sh_d = (unsigned)t; sh_cntgt = sufd1;
        }
        __syncthreads();
    };

    find_digit(rem);
    const int dbin = (int)sh_d;
    rem -= (int)sh_cntgt;

    // compact threshold-bin candidates (expected ~tens)
#pragma unroll
    for (int j = 0; j < 16; j++) {
        if (binOf(val[j]) == dbin) {
            int slot = atomicAdd(&sh_ncand, 1);
            candKey[slot] = ukey[j];
        }
    }
    __syncthreads();
    const int nc = sh_ncand;

    // ---- level 2: bit-exact 4-pass radix on candidates ----
    unsigned prefix = 0u;
    for (int pass = 0; pass < 4; pass++) {
        const int shift = 24 - 8 * pass;
        hist[t] = 0u;
        __syncthreads();
        for (int i = t; i < nc; i += 256) {
            unsigned u2 = candKey[i];
            if (pass == 0 || (u2 >> (shift + 8)) == (prefix >> (shift + 8)))
                atomicAdd(&hist[(u2 >> shift) & 255u], 1u);
        }
        __syncthreads();
        find_digit(rem);
        prefix |= (sh_d << shift);
        rem -= (int)sh_cntgt;
    }
    const unsigned T = prefix;
    const int need = rem;
    const float mT = keyToF(T);   // softmax shift: shift-invariant, any m works

    // stable tie-break: exclusive prefix of per-thread equal counts (wave scan)
    int eqc = 0;
#pragma unroll
    for (int j = 0; j < 16; j++) if (ukey[j] == T) eqc++;
    int vinc = eqc;
#pragma unroll
    for (int off = 1; off < 64; off <<= 1) {
        int o = __shfl_up(vinc, off);
        if (l >= off) vinc += o;
    }
    if (l == 63) wred[w] = (unsigned)vinc;
    __syncthreads();
    int addlow = 0;
#pragma unroll
    for (int w2 = 0; w2 < 4; w2++) if (w2 < w) addlow += (int)wred[w2];
    const int eqexcl = vinc - eqc + addlow;

    // selection + exp: u>T unconditional, ties = exp(0) = 1.0f exactly
    float pv[16];
    float le = 0.f;
#pragma unroll
    for (int j = 0; j < 16; j++) {
        float e = 0.f;
        if (ukey[j] > T) { e = __expf(val[j] - mT); le += e; }
        pv[j] = e;
    }
    if (eqc) {
        int seen = 0;
#pragma unroll
        for (int j = 0; j < 16; j++) {
            if (ukey[j] == T) {
                if (eqexcl + seen < need) { pv[j] = 1.0f; le += 1.0f; }
                seen++;
            }
        }
    }

    // sum reduce
#pragma unroll
    for (int off = 32; off > 0; off >>= 1) {
        float o = __shfl_down(le, off);
        if (l + off < 64) le += o;
    }
    if (l == 0) wsum[w] = le;
    __syncthreads();
    const float inv = 1.0f / (wsum[0] + wsum[1] + wsum[2] + wsum[3]);

    half8 ra, rb;
#pragma unroll
    for (int j = 0; j < 8; j++) {
        ra[j] = (_Float16)(pv[j] * inv);
        rb[j] = (_Float16)(pv[j + 8] * inv);
    }
    _Float16* Pr = P + (size_t)blockIdx.x * PSTRIDE + t * 16;
    *(half8*)Pr       = ra;
    *(half8*)(Pr + 8) = rb;
}

// ---------- kernel 6: out[b][c][n] = sum_m Vt[c][m] * P[n][m] via MFMA f16 ----------
__global__ __launch_bounds__(256) void av_gemm(
        const _Float16* __restrict__ Vt, const _Float16* __restrict__ P,
        float* __restrict__ out) {
    __shared__ _Float16 As[64][72];
    __shared__ _Float16 Bs[64][72];

    const int t    = threadIdx.x;
    const int wave = t >> 6;
    const int l    = t & 63;
    const int wr   = wave >> 1;
    const int wc   = wave & 1;
    const int bxn  = blockIdx.x;
    const int byc  = blockIdx.y;
    const int b    = blockIdx.z;

    const int r = t >> 2;
    const int q = t & 3;

    const _Float16* Abase = Vt + ((size_t)((b << 8) + byc * 64 + r)) * NN + q * 16;
    const _Float16* Bbase = P + ((size_t)(b * NN + bxn * 64 + r)) * PSTRIDE + q * 16;

    floatx4 acc[2][2];
#pragma unroll
    for (int i = 0; i < 2; i++)
#pragma unroll
        for (int j = 0; j < 2; j++) acc[i][j] = (floatx4)0.0f;

    const int rowA = l & 15;
    const int koff = (l >> 4) * 8;

    for (int kc = 0; kc < NN; kc += 64) {
        const uint4* ap = (const uint4*)(Abase + kc);
        const uint4* bp = (const uint4*)(Bbase + kc);
        uint4 a0 = ap[0], a1 = ap[1];
        uint4 b0 = bp[0], b1 = bp[1];
        *(uint4*)&As[r][q * 16]     = a0;
        *(uint4*)&As[r][q * 16 + 8] = a1;
        *(uint4*)&Bs[r][q * 16]     = b0;
        *(uint4*)&Bs[r][q * 16 + 8] = b1;
        __syncthreads();
#pragma unroll
        for (int ks = 0; ks < 64; ks += 32) {
            half8 af[2], bf[2];
#pragma unroll
            for (int mi = 0; mi < 2; mi++)
                af[mi] = *(const half8*)&As[wr * 32 + mi * 16 + rowA][ks + koff];
#pragma unroll
            for (int ni = 0; ni < 2; ni++)
                bf[ni] = *(const half8*)&Bs[wc * 32 + ni * 16 + rowA][ks + koff];
#pragma unroll
            for (int mi = 0; mi < 2; mi++)
#pragma unroll
                for (int ni = 0; ni < 2; ni++)
                    acc[mi][ni] = __builtin_amdgcn_mfma_f32_16x16x32_f16(
                        af[mi], bf[ni], acc[mi][ni], 0, 0, 0);
        }
        __syncthreads();
    }

#pragma unroll
    for (int mi = 0; mi < 2; mi++)
#pragma unroll
        for (int ni = 0; ni < 2; ni++) {
            int col = bxn * 64 + wc * 32 + ni * 16 + (l & 15);
#pragma unroll
            for (int rg = 0; rg < 4; rg++) {
                int row = byc * 64 + wr * 32 + mi * 16 + (l >> 4) * 4 + rg;
                out[((size_t)((b << 8) + row) << 12) + col] = acc[mi][ni][rg];
            }
        }
}

extern "C" void kernel_launch(void* const* d_in, const int* in_sizes, int n_in,
                              void* d_out, int out_size, void* d_ws, size_t ws_size,
                              hipStream_t stream) {
    const float* x  = (const float*)d_in[0];
    const float* Wq = (const float*)d_in[1];
    const float* bq = (const float*)d_in[2];
    const float* Wk = (const float*)d_in[3];
    const float* bk = (const float*)d_in[4];
    const float* Wv = (const float*)d_in[5];
    const float* bv = (const float*)d_in[6];
    float* out = (float*)d_out;

    char* ws = (char*)d_ws;
    _Float16* Wcat = (_Float16*)ws;                            // 1.18 MB
    _Float16* Qcat = (_Float16*)(ws + 1179648);                // 12.6 MB
    _Float16* Kcat = (_Float16*)(ws + 1179648 + 12582912);     // 12.6 MB
    _Float16* Vt   = (_Float16*)(ws + 1179648 + 2 * 12582912); // 4 MB
    float*    S    = (float*)   (ws + 1179648 + 2 * 12582912 + 4194304); // 128 MB
    _Float16* xcat = (_Float16*)S;   // xcat dead before score_gemm writes S
    _Float16* P    = (_Float16*)S;   // P aliases S rows (proven safe)

    xpose_kernel<<<dim3(64, 4, BATCH), 256, 0, stream>>>(x, xcat);
    wcat_kernel<<<768, 256, 0, stream>>>(Wq, Wk, Wv, Wcat);
    proj_gemm<<<dim3(128, 1, 3), 256, 0, stream>>>(xcat, Wcat, bq, bk, bv,
                                                   Qcat, Kcat, Vt);
    score_gemm<<<dim3(16, 16, BATCH), 512, 0, stream>>>(Qcat, Kcat, S);
    select_scatter<<<BATCH * NN, 256, 0, stream>>>(S, P);
    av_gemm<<<dim3(64, 4, BATCH), 256, 0, stream>>>(Vt, P, out);
}

// Round 9
// 243.604 us; speedup vs baseline: 1.0835x; 1.0835x over previous
//
#include <hip/hip_runtime.h>
#include <hip/hip_bf16.h>
#include <math.h>

#define BATCH 2
#define CC    256
#define NN    4096
#define KK    409          // max(1, int(0.1*4096))
#define KCAT  768          // split-fp16 concat K
#define SCALE 0.0625f      // 1/sqrt(256)
#define PSTRIDE 8192       // P row stride in halfs (P aliases S rows)

typedef _Float16 half8 __attribute__((ext_vector_type(8)));
typedef float    floatx4 __attribute__((ext_vector_type(4)));

// async global->LDS, 16B per lane; LDS dest = wave-uniform base + lane*16
typedef __attribute__((address_space(3))) unsigned       lds_u32;
typedef __attribute__((address_space(1))) const unsigned glb_u32;
__device__ __forceinline__ void gload16(const void* g, void* l) {
    __builtin_amdgcn_global_load_lds((glb_u32*)g, (lds_u32*)l, 16, 0, 0);
}

// ---------- helpers: order-preserving float<->uint key ----------
__device__ __forceinline__ unsigned fkey(float f) {
    unsigned u = __float_as_uint(f);
    return (u & 0x80000000u) ? ~u : (u | 0x80000000u);
}
__device__ __forceinline__ float keyToF(unsigned k) {
    unsigned u = (k & 0x80000000u) ? (k ^ 0x80000000u) : ~k;
    return __uint_as_float(u);
}

// ---------- kernel 1: xpose (by<4) + wcat (by==4) merged ----------
// by<4: x[b][c][n] f32 -> xcat[b*N+n][768] = [hi, lo, hi]
// by==4: W[o][c] -> Wcat[mat][o][768] = [whi, whi, wlo]
__global__ __launch_bounds__(256) void xpose_wcat_kernel(
        const float* __restrict__ x,
        const float* __restrict__ Wq, const float* __restrict__ Wk,
        const float* __restrict__ Wv,
        _Float16* __restrict__ xcat, _Float16* __restrict__ Wcat) {
    const int t  = threadIdx.x;
    if (blockIdx.y == 4) {
        int idx = (blockIdx.z * 64 + blockIdx.x) * 256 + t;
#pragma unroll
        for (int k = 0; k < 6; k++) {
            int e = idx + k * 32768;              // covers 3*65536 exactly
            int mat = e >> 16;
            int o   = (e >> 8) & 255;
            int c   = e & 255;
            const float* W = (mat == 0) ? Wq : (mat == 1) ? Wk : Wv;
            float v = W[o * 256 + c];
            _Float16 hi = (_Float16)v;
            _Float16 lo = (_Float16)(v - (float)hi);
            _Float16* wr = Wcat + ((size_t)(mat * 256 + o)) * KCAT;
            wr[c] = hi; wr[256 + c] = hi; wr[512 + c] = lo;
        }
        return;
    }

    __shared__ float xs[64][68];
    const int n0 = blockIdx.x * 64;
    const int c0 = blockIdx.y * 64;
    const int b  = blockIdx.z;

    {
        const int ci = t >> 2;
        const int j  = (t & 3) * 16;
        const float* xp = x + ((size_t)((b << 8) + c0 + ci)) * NN + n0 + j;
        float4 a0 = ((const float4*)xp)[0];
        float4 a1 = ((const float4*)xp)[1];
        float4 a2 = ((const float4*)xp)[2];
        float4 a3 = ((const float4*)xp)[3];
        *(float4*)&xs[ci][j]      = a0;
        *(float4*)&xs[ci][j + 4]  = a1;
        *(float4*)&xs[ci][j + 8]  = a2;
        *(float4*)&xs[ci][j + 12] = a3;
    }
    __syncthreads();

    const int n = t >> 2;
    const int g0 = t & 3;
    _Float16* xr = xcat + ((size_t)(b * NN + n0 + n)) * KCAT + c0;
#pragma unroll
    for (int gg = 0; gg < 2; gg++) {
        int g = g0 + gg * 4;
        half8 hi, lo;
#pragma unroll
        for (int k = 0; k < 8; k++) {
            float v = xs[g * 8 + k][n];
            _Float16 h = (_Float16)v;
            hi[k] = h;
            lo[k] = (_Float16)(v - (float)h);
        }
        *(half8*)(xr + g * 8)       = hi;
        *(half8*)(xr + 256 + g * 8) = lo;
        *(half8*)(xr + 512 + g * 8) = hi;
    }
}

// ---------- kernel 2: projections via MFMA, 128x128 tile, K=768 ----------
// async swizzled staging (same pattern as score_gemm); epilogues unchanged
__global__ __launch_bounds__(256) void proj_gemm(
        const _Float16* __restrict__ xcat, const _Float16* __restrict__ Wcat,
        const float* __restrict__ bq, const float* __restrict__ bk,
        const float* __restrict__ bv,
        _Float16* __restrict__ Qcat, _Float16* __restrict__ Kcat,
        _Float16* __restrict__ Vt) {
    __shared__ _Float16 As[128][64];
    __shared__ _Float16 Bs[128][64];

    const int t    = threadIdx.x;
    const int wave = t >> 6;
    const int l    = t & 63;
    const int wr   = wave >> 1;
    const int wc   = wave & 1;
    const int mat  = blockIdx.z;

    int bym, bxn;
    if (mat < 2) { bym = blockIdx.x >> 1; bxn = blockIdx.x & 1; }
    else         { bym = blockIdx.x & 1;  bxn = blockIdx.x >> 1; }

    const int lr = l >> 3;
    const int gg = (l & 7) ^ lr;

    const _Float16* At;
    const _Float16* Bt;
    if (mat < 2) {
        At = xcat + ((size_t)(bym * 128)) * KCAT;
        Bt = Wcat + ((size_t)(mat * 256 + bxn * 128)) * KCAT;
    } else {
        At = Wcat + ((size_t)(512 + bym * 128)) * KCAT;
        Bt = xcat + ((size_t)(bxn * 128)) * KCAT;
    }
    const size_t lane_off = (size_t)lr * KCAT + gg * 8;

    floatx4 acc[4][4];
#pragma unroll
    for (int i = 0; i < 4; i++)
#pragma unroll
        for (int j = 0; j < 4; j++) acc[i][j] = (floatx4)0.0f;

    const int rowA = l & 15;
    const int sg0  = (l >> 4) ^ (l & 7);
    const int sg1  = sg0 ^ 4;

    for (int kc = 0; kc < KCAT; kc += 64) {
#pragma unroll
        for (int s = 0; s < 4; s++) {
            const int seg = wave * 4 + s;
            gload16(At + (size_t)seg * 8 * KCAT + lane_off + kc, &As[seg * 8][0]);
            gload16(Bt + (size_t)seg * 8 * KCAT + lane_off + kc, &Bs[seg * 8][0]);
        }
        __syncthreads();
#pragma unroll
        for (int ks = 0; ks < 2; ks++) {
            const int sg = ks ? sg1 : sg0;
            half8 af[4], bf[4];
#pragma unroll
            for (int mi = 0; mi < 4; mi++)
                af[mi] = *(const half8*)&As[wr * 64 + mi * 16 + rowA][sg * 8];
#pragma unroll
            for (int ni = 0; ni < 4; ni++)
                bf[ni] = *(const half8*)&Bs[wc * 64 + ni * 16 + rowA][sg * 8];
#pragma unroll
            for (int mi = 0; mi < 4; mi++)
#pragma unroll
                for (int ni = 0; ni < 4; ni++)
                    acc[mi][ni] = __builtin_amdgcn_mfma_f32_16x16x32_f16(
                        af[mi], bf[ni], acc[mi][ni], 0, 0, 0);
        }
        __syncthreads();
    }

    if (mat < 2) {
        const float* bias = (mat == 0) ? bq : bk;
        _Float16* Out = (mat == 0) ? Qcat : Kcat;
#pragma unroll
        for (int ni = 0; ni < 4; ni++) {
            int ch = bxn * 128 + wc * 64 + ni * 16 + (l & 15);
            float bb = bias[ch];
#pragma unroll
            for (int mi = 0; mi < 4; mi++)
#pragma unroll
                for (int rg = 0; rg < 4; rg++) {
                    int token = bym * 128 + wr * 64 + mi * 16 + (l >> 4) * 4 + rg;
                    float v = acc[mi][ni][rg] + bb;
                    _Float16 hi = (_Float16)v;
                    _Float16 lo = (_Float16)(v - (float)hi);
                    _Float16* p = Out + (size_t)token * KCAT + ch;
                    if (mat == 0) { p[0] = hi; p[256] = lo; p[512] = hi; }
                    else          { p[0] = hi; p[256] = hi; p[512] = lo; }
                }
        }
    } else {
#pragma unroll
        for (int mi = 0; mi < 4; mi++)
#pragma unroll
            for (int rg = 0; rg < 4; rg++) {
                int ch = bym * 128 + wr * 64 + mi * 16 + (l >> 4) * 4 + rg;
                float bb = bv[ch];
#pragma unroll
                for (int ni = 0; ni < 4; ni++) {
                    int col = bxn * 128 + wc * 64 + ni * 16 + (l & 15);
                    int b = col >> 12, n = col & 4095;
                    Vt[((size_t)((b << 8) + ch)) * NN + n] =
                        (_Float16)(acc[mi][ni][rg] + bb);
                }
            }
    }
}

// ---------- kernel 3: S = (Qcat @ Kcat^T) * SCALE via MFMA f16 ----------
// 256x256 block tile, 512 thr = 8 waves (4x2), async swizzled staging.
__global__ __launch_bounds__(512, 2) void score_gemm(
        const _Float16* __restrict__ Qcat, const _Float16* __restrict__ Kcat,
        float* __restrict__ S) {
    __shared__ _Float16 As[256][64];
    __shared__ _Float16 Bs[256][64];

    const int t    = threadIdx.x;
    const int wave = t >> 6;             // 0..7
    const int l    = t & 63;
    const int wr   = wave >> 1;          // 0..3 (M)
    const int wc   = wave & 1;           // 0..1 (N)
    const int bxn  = blockIdx.x;
    const int bym  = blockIdx.y;
    const int b    = blockIdx.z;

    const int lr = l >> 3;
    const int gg = (l & 7) ^ lr;

    const _Float16* At = Qcat + ((size_t)((b << 12) + bym * 256)) * KCAT;
    const _Float16* Bt = Kcat + ((size_t)((b << 12) + bxn * 256)) * KCAT;
    const size_t lane_off = (size_t)lr * KCAT + gg * 8;

    floatx4 acc[4][8];
#pragma unroll
    for (int i = 0; i < 4; i++)
#pragma unroll
        for (int j = 0; j < 8; j++) acc[i][j] = (floatx4)0.0f;

    const int rowA = l & 15;
    const int sg0  = (l >> 4) ^ (l & 7);
    const int sg1  = sg0 ^ 4;

    for (int kc = 0; kc < KCAT; kc += 64) {
#pragma unroll
        for (int s = 0; s < 4; s++) {
            const int seg = wave * 4 + s;
            gload16(At + (size_t)seg * 8 * KCAT + lane_off + kc, &As[seg * 8][0]);
            gload16(Bt + (size_t)seg * 8 * KCAT + lane_off + kc, &Bs[seg * 8][0]);
        }
        __syncthreads();
#pragma unroll
        for (int ks = 0; ks < 2; ks++) {
            const int sg = ks ? sg1 : sg0;
            half8 af[4], bf[8];
#pragma unroll
            for (int mi = 0; mi < 4; mi++)
                af[mi] = *(const half8*)&As[wr * 64 + mi * 16 + rowA][sg * 8];
#pragma unroll
            for (int ni = 0; ni < 8; ni++)
                bf[ni] = *(const half8*)&Bs[wc * 128 + ni * 16 + rowA][sg * 8];
#pragma unroll
            for (int mi = 0; mi < 4; mi++)
#pragma unroll
                for (int ni = 0; ni < 8; ni++)
                    acc[mi][ni] = __builtin_amdgcn_mfma_f32_16x16x32_f16(
                        af[mi], bf[ni], acc[mi][ni], 0, 0, 0);
        }
        __syncthreads();
    }

    float* Sb = S + ((size_t)b << 24);
#pragma unroll
    for (int mi = 0; mi < 4; mi++)
#pragma unroll
        for (int ni = 0; ni < 8; ni++) {
            int col = bxn * 256 + wc * 128 + ni * 16 + (l & 15);
#pragma unroll
            for (int rg = 0; rg < 4; rg++) {
                int row = bym * 256 + wr * 64 + mi * 16 + (l >> 4) * 4 + rg;
                Sb[((size_t)row << 12) + col] = acc[mi][ni][rg] * SCALE;
            }
        }
}

// ---------- kernel 4: per-row exact top-k + softmax -> dense fp16 P row ----------
// level 1: linear-value 256-bin histogram; level 2: single-wave stable
// rank-select on the threshold bin's candidates (radix fallback if nc>64).
__global__ __launch_bounds__(256) void select_scatter(
        const float* __restrict__ S, _Float16* __restrict__ P) {
    __shared__ unsigned hist[256];
    __shared__ unsigned scan[256];
    __shared__ unsigned candKey[NN];     // worst case: all in one bin
    __shared__ unsigned wred[4];
    __shared__ float    fmn[4], fmx[4], wsum[4];
    __shared__ unsigned sh_d, sh_cntgt, sh_T;
    __shared__ int      sh_ncand, sh_need;

    const int t = threadIdx.x;
    const int l = t & 63;
    const int w = t >> 6;

    float    val[16];
    unsigned ukey[16];
    {
        const float*  Srow = S + ((size_t)blockIdx.x << 12);
        const float4* sp   = (const float4*)(Srow + t * 16);
#pragma unroll
        for (int jj = 0; jj < 4; jj++) {
            float4 v = sp[jj];
            val[jj * 4 + 0] = v.x; val[jj * 4 + 1] = v.y;
            val[jj * 4 + 2] = v.z; val[jj * 4 + 3] = v.w;
        }
#pragma unroll
        for (int j = 0; j < 16; j++) ukey[j] = fkey(val[j]);
    }

    // row min/max via wave reduce
    float lmin = val[0], lmax = val[0];
#pragma unroll
    for (int j = 1; j < 16; j++) {
        lmin = fminf(lmin, val[j]); lmax = fmaxf(lmax, val[j]);
    }
#pragma unroll
    for (int off = 32; off > 0; off >>= 1) {
        float a = __shfl_down(lmin, off);
        float b = __shfl_down(lmax, off);
        if (l + off < 64) { lmin = fminf(lmin, a); lmax = fmaxf(lmax, b); }
    }
    if (l == 0) { fmn[w] = lmin; fmx[w] = lmax; }

    hist[t] = 0u;
    if (t == 0) sh_ncand = 0;
    __syncthreads();
    const float fmin = fminf(fminf(fmn[0], fmn[1]), fminf(fmn[2], fmn[3]));
    const float fmax = fmaxf(fmaxf(fmx[0], fmx[1]), fmaxf(fmx[2], fmx[3]));
    const float range = fmax - fmin;
    const float bscale = (range > 1e-20f) ? 255.0f / range : 0.0f;

    auto binOf = [&](float v) -> int {
        int bin = (int)((v - fmin) * bscale);
        return bin < 0 ? 0 : (bin > 255 ? 255 : bin);
    };

    // ---- level 1: linear histogram ----
#pragma unroll
    for (int j = 0; j < 16; j++) atomicAdd(&hist[binOf(val[j])], 1u);
    __syncthreads();

    int rem = KK;

    auto find_digit = [&](int remv) {
        unsigned v = hist[t];
#pragma unroll
        for (int off = 1; off < 64; off <<= 1) {
            unsigned o = __shfl_down(v, off);
            if (l + off < 64) v += o;
        }
        if (l == 0) wred[w] = v;
        __syncthreads();
        unsigned add = 0u;
#pragma unroll
        for (int w2 = 0; w2 < 4; w2++) if (w2 > w) add += wred[w2];
        scan[t] = v + add;
        __syncthreads();
        unsigned sufd  = scan[t];
        unsigned sufd1 = (t < 255) ? scan[t + 1] : 0u;
        if (sufd >= (unsigned)remv && sufd1 < (unsigned)remv) {
            sh_d = (unsigned)t; sh_cntgt = sufd1;
        }
        __syncthreads();
    };

    find_digit(rem);
    const int dbin = (int)sh_d;
    rem -= (int)sh_cntgt;

    // compact threshold-bin candidates (expected ~tens)
#pragma unroll
    for (int j = 0; j < 16; j++) {
        if (binOf(val[j]) == dbin) {
            int slot = atomicAdd(&sh_ncand, 1);
            candKey[slot] = ukey[j];
        }
    }
    __syncthreads();
    const int nc = sh_ncand;

    // ---- level 2: exact rem-th largest among candidates ----
    if (nc <= 64) {
        if (w == 0) {
            unsigned kl = (l < nc) ? candKey[l] : 0u;  // 0 = -inf key (real keys > 0)
            int r = 0, g = 0;
            for (int j = 0; j < 64; j++) {
                unsigned kj = __shfl(kl, j);
                bool gt = kj > kl;
                g += gt ? 1 : 0;
                r += (gt || (kj == kl && j < l)) ? 1 : 0;  // stable rank
            }
            if (r == rem - 1) { sh_T = kl; sh_need = rem - g; }
        }
    } else {
        unsigned prefix = 0u;
        int rem2 = rem;
        for (int pass = 0; pass < 4; pass++) {
            const int shift = 24 - 8 * pass;
            hist[t] = 0u;
            __syncthreads();
            for (int i = t; i < nc; i += 256) {
                unsigned u2 = candKey[i];
                if (pass == 0 || (u2 >> (shift + 8)) == (prefix >> (shift + 8)))
                    atomicAdd(&hist[(u2 >> shift) & 255u], 1u);
            }
            __syncthreads();
            find_digit(rem2);
            prefix |= (sh_d << shift);
            rem2 -= (int)sh_cntgt;
        }
        if (t == 0) { sh_T = prefix; sh_need = rem2; }
    }
    __syncthreads();
    const unsigned T = sh_T;
    const int need = sh_need;
    const float mT = keyToF(T);   // softmax shift: shift-invariant, any m works

    // stable tie-break: exclusive prefix of per-thread equal counts (wave scan)
    int eqc = 0;
#pragma unroll
    for (int j = 0; j < 16; j++) if (ukey[j] == T) eqc++;
    int vinc = eqc;
#pragma unroll
    for (int off = 1; off < 64; off <<= 1) {
        int o = __shfl_up(vinc, off);
        if (l >= off) vinc += o;
    }
    if (l == 63) wred[w] = (unsigned)vinc;
    __syncthreads();
    int addlow = 0;
#pragma unroll
    for (int w2 = 0; w2 < 4; w2++) if (w2 < w) addlow += (int)wred[w2];
    const int eqexcl = vinc - eqc + addlow;

    // selection + exp: u>T unconditional, ties = exp(0) = 1.0f exactly
    float pv[16];
    float le = 0.f;
#pragma unroll
    for (int j = 0; j < 16; j++) {
        float e = 0.f;
        if (ukey[j] > T) { e = __expf(val[j] - mT); le += e; }
        pv[j] = e;
    }
    if (eqc) {
        int seen = 0;
#pragma unroll
        for (int j = 0; j < 16; j++) {
            if (ukey[j] == T) {
                if (eqexcl + seen < need) { pv[j] = 1.0f; le += 1.0f; }
                seen++;
            }
        }
    }

    // sum reduce
#pragma unroll
    for (int off = 32; off > 0; off >>= 1) {
        float o = __shfl_down(le, off);
        if (l + off < 64) le += o;
    }
    if (l == 0) wsum[w] = le;
    __syncthreads();
    const float inv = 1.0f / (wsum[0] + wsum[1] + wsum[2] + wsum[3]);

    half8 ra, rb;
#pragma unroll
    for (int j = 0; j < 8; j++) {
        ra[j] = (_Float16)(pv[j] * inv);
        rb[j] = (_Float16)(pv[j + 8] * inv);
    }
    _Float16* Pr = P + (size_t)blockIdx.x * PSTRIDE + t * 16;
    *(half8*)Pr       = ra;
    *(half8*)(Pr + 8) = rb;
}

// ---------- kernel 5: out[b][c][n] = sum_m Vt[c][m] * P[n][m] via MFMA f16 ----------
// async swizzled staging, K-chunk 128 (halved barrier count)
__global__ __launch_bounds__(256) void av_gemm(
        const _Float16* __restrict__ Vt, const _Float16* __restrict__ P,
        float* __restrict__ out) {
    __shared__ _Float16 As0[64][64], As1[64][64];
    __shared__ _Float16 Bs0[64][64], Bs1[64][64];

    const int t    = threadIdx.x;
    const int wave = t >> 6;
    const int l    = t & 63;
    const int wr   = wave >> 1;
    const int wc   = wave & 1;
    const int bxn  = blockIdx.x;
    const int byc  = blockIdx.y;
    const int b    = blockIdx.z;

    const int lr = l >> 3;
    const int gg = (l & 7) ^ lr;

    const _Float16* At = Vt + ((size_t)((b << 8) + byc * 64)) * NN;
    const _Float16* Bt = P + ((size_t)(b * NN + bxn * 64)) * PSTRIDE;
    const size_t lane_offA = (size_t)lr * NN + gg * 8;
    const size_t lane_offB = (size_t)lr * PSTRIDE + gg * 8;

    floatx4 acc[2][2];
#pragma unroll
    for (int i = 0; i < 2; i++)
#pragma unroll
        for (int j = 0; j < 2; j++) acc[i][j] = (floatx4)0.0f;

    const int rowA   = l & 15;
    const int sgbase = (l >> 4) ^ (l & 7);

    for (int kc = 0; kc < NN; kc += 128) {
#pragma unroll
        for (int s = 0; s < 2; s++) {
            const int seg = wave * 2 + s;
            gload16(At + (size_t)seg * 8 * NN + lane_offA + kc,           &As0[seg * 8][0]);
            gload16(At + (size_t)seg * 8 * NN + lane_offA + kc + 64,      &As1[seg * 8][0]);
            gload16(Bt + (size_t)seg * 8 * PSTRIDE + lane_offB + kc,      &Bs0[seg * 8][0]);
            gload16(Bt + (size_t)seg * 8 * PSTRIDE + lane_offB + kc + 64, &Bs1[seg * 8][0]);
        }
        __syncthreads();
#pragma unroll
        for (int st = 0; st < 4; st++) {
            const _Float16 (*Ap)[64] = (st < 2) ? As0 : As1;
            const _Float16 (*Bp)[64] = (st < 2) ? Bs0 : Bs1;
            const int sg = sgbase ^ ((st & 1) ? 4 : 0);
            half8 af[2], bf[2];
#pragma unroll
            for (int mi = 0; mi < 2; mi++)
                af[mi] = *(const half8*)&Ap[wr * 32 + mi * 16 + rowA][sg * 8];
#pragma unroll
            for (int ni = 0; ni < 2; ni++)
                bf[ni] = *(const half8*)&Bp[wc * 32 + ni * 16 + rowA][sg * 8];
#pragma unroll
            for (int mi = 0; mi < 2; mi++)
#pragma unroll
                for (int ni = 0; ni < 2; ni++)
                    acc[mi][ni] = __builtin_amdgcn_mfma_f32_16x16x32_f16(
                        af[mi], bf[ni], acc[mi][ni], 0, 0, 0);
        }
        __syncthreads();
    }

#pragma unroll
    for (int mi = 0; mi < 2; mi++)
#pragma unroll
        for (int ni = 0; ni < 2; ni++) {
            int col = bxn * 64 + wc * 32 + ni * 16 + (l & 15);
#pragma unroll
            for (int rg = 0; rg < 4; rg++) {
                int row = byc * 64 + wr * 32 + mi * 16 + (l >> 4) * 4 + rg;
                out[((size_t)((b << 8) + row) << 12) + col] = acc[mi][ni][rg];
            }
        }
}

extern "C" void kernel_launch(void* const* d_in, const int* in_sizes, int n_in,
                              void* d_out, int out_size, void* d_ws, size_t ws_size,
                              hipStream_t stream) {
    const float* x  = (const float*)d_in[0];
    const float* Wq = (const float*)d_in[1];
    const float* bq = (const float*)d_in[2];
    const float* Wk = (const float*)d_in[3];
    const float* bk = (const float*)d_in[4];
    const float* Wv = (const float*)d_in[5];
    const float* bv = (const float*)d_in[6];
    float* out = (float*)d_out;

    char* ws = (char*)d_ws;
    _Float16* Wcat = (_Float16*)ws;                            // 1.18 MB
    _Float16* Qcat = (_Float16*)(ws + 1179648);                // 12.6 MB
    _Float16* Kcat = (_Float16*)(ws + 1179648 + 12582912);     // 12.6 MB
    _Float16* Vt   = (_Float16*)(ws + 1179648 + 2 * 12582912); // 4 MB
    float*    S    = (float*)   (ws + 1179648 + 2 * 12582912 + 4194304); // 128 MB
    _Float16* xcat = (_Float16*)S;   // xcat dead before score_gemm writes S
    _Float16* P    = (_Float16*)S;   // P aliases S rows (proven safe)

    xpose_wcat_kernel<<<dim3(64, 5, BATCH), 256, 0, stream>>>(x, Wq, Wk, Wv,
                                                              xcat, Wcat);
    proj_gemm<<<dim3(128, 1, 3), 256, 0, stream>>>(xcat, Wcat, bq, bk, bv,
                                                   Qcat, Kcat, Vt);
    score_gemm<<<dim3(16, 16, BATCH), 512, 0, stream>>>(Qcat, Kcat, S);
    select_scatter<<<BATCH * NN, 256, 0, stream>>>(S, P);
    av_gemm<<<dim3(64, 4, BATCH), 256, 0, stream>>>(Vt, P, out);
}

// Round 10
// 243.526 us; speedup vs baseline: 1.0838x; 1.0003x over previous
//
#include <hip/hip_runtime.h>
#include <hip/hip_bf16.h>
#include <math.h>

#define BATCH 2
#define CC    256
#define NN    4096
#define KK    409          // max(1, int(0.1*4096))
#define KCAT  768          // split-fp16 concat K
#define SCALE 0.0625f      // 1/sqrt(256)
#define PSTRIDE 8192       // P row stride in halfs (P aliases S rows)

typedef _Float16 half8 __attribute__((ext_vector_type(8)));
typedef float    floatx4 __attribute__((ext_vector_type(4)));

// async global->LDS, 16B per lane; LDS dest = wave-uniform base + lane*16
typedef __attribute__((address_space(3))) unsigned       lds_u32;
typedef __attribute__((address_space(1))) const unsigned glb_u32;
__device__ __forceinline__ void gload16(const void* g, void* l) {
    __builtin_amdgcn_global_load_lds((glb_u32*)g, (lds_u32*)l, 16, 0, 0);
}

// ---------- helpers: order-preserving float<->uint key ----------
__device__ __forceinline__ unsigned fkey(float f) {
    unsigned u = __float_as_uint(f);
    return (u & 0x80000000u) ? ~u : (u | 0x80000000u);
}
__device__ __forceinline__ float keyToF(unsigned k) {
    unsigned u = (k & 0x80000000u) ? (k ^ 0x80000000u) : ~k;
    return __uint_as_float(u);
}

// ---------- kernel 1: xpose (by<4) + wcat (by==4) merged ----------
__global__ __launch_bounds__(256) void xpose_wcat_kernel(
        const float* __restrict__ x,
        const float* __restrict__ Wq, const float* __restrict__ Wk,
        const float* __restrict__ Wv,
        _Float16* __restrict__ xcat, _Float16* __restrict__ Wcat) {
    const int t  = threadIdx.x;
    if (blockIdx.y == 4) {
        int idx = (blockIdx.z * 64 + blockIdx.x) * 256 + t;
#pragma unroll
        for (int k = 0; k < 6; k++) {
            int e = idx + k * 32768;              // covers 3*65536 exactly
            int mat = e >> 16;
            int o   = (e >> 8) & 255;
            int c   = e & 255;
            const float* W = (mat == 0) ? Wq : (mat == 1) ? Wk : Wv;
            float v = W[o * 256 + c];
            _Float16 hi = (_Float16)v;
            _Float16 lo = (_Float16)(v - (float)hi);
            _Float16* wr = Wcat + ((size_t)(mat * 256 + o)) * KCAT;
            wr[c] = hi; wr[256 + c] = hi; wr[512 + c] = lo;
        }
        return;
    }

    __shared__ float xs[64][68];
    const int n0 = blockIdx.x * 64;
    const int c0 = blockIdx.y * 64;
    const int b  = blockIdx.z;

    {
        const int ci = t >> 2;
        const int j  = (t & 3) * 16;
        const float* xp = x + ((size_t)((b << 8) + c0 + ci)) * NN + n0 + j;
        float4 a0 = ((const float4*)xp)[0];
        float4 a1 = ((const float4*)xp)[1];
        float4 a2 = ((const float4*)xp)[2];
        float4 a3 = ((const float4*)xp)[3];
        *(float4*)&xs[ci][j]      = a0;
        *(float4*)&xs[ci][j + 4]  = a1;
        *(float4*)&xs[ci][j + 8]  = a2;
        *(float4*)&xs[ci][j + 12] = a3;
    }
    __syncthreads();

    const int n = t >> 2;
    const int g0 = t & 3;
    _Float16* xr = xcat + ((size_t)(b * NN + n0 + n)) * KCAT + c0;
#pragma unroll
    for (int gg = 0; gg < 2; gg++) {
        int g = g0 + gg * 4;
        half8 hi, lo;
#pragma unroll
        for (int k = 0; k < 8; k++) {
            float v = xs[g * 8 + k][n];
            _Float16 h = (_Float16)v;
            hi[k] = h;
            lo[k] = (_Float16)(v - (float)h);
        }
        *(half8*)(xr + g * 8)       = hi;
        *(half8*)(xr + 256 + g * 8) = lo;
        *(half8*)(xr + 512 + g * 8) = hi;
    }
}

// ---------- kernel 2: projections via MFMA, 128x128 tile, K=768 ----------
__global__ __launch_bounds__(256) void proj_gemm(
        const _Float16* __restrict__ xcat, const _Float16* __restrict__ Wcat,
        const float* __restrict__ bq, const float* __restrict__ bk,
        const float* __restrict__ bv,
        _Float16* __restrict__ Qcat, _Float16* __restrict__ Kcat,
        _Float16* __restrict__ Vt) {
    __shared__ _Float16 As[128][64];
    __shared__ _Float16 Bs[128][64];

    const int t    = threadIdx.x;
    const int wave = t >> 6;
    const int l    = t & 63;
    const int wr   = wave >> 1;
    const int wc   = wave & 1;
    const int mat  = blockIdx.z;

    int bym, bxn;
    if (mat < 2) { bym = blockIdx.x >> 1; bxn = blockIdx.x & 1; }
    else         { bym = blockIdx.x & 1;  bxn = blockIdx.x >> 1; }

    const int lr = l >> 3;
    const int gg = (l & 7) ^ lr;

    const _Float16* At;
    const _Float16* Bt;
    if (mat < 2) {
        At = xcat + ((size_t)(bym * 128)) * KCAT;
        Bt = Wcat + ((size_t)(mat * 256 + bxn * 128)) * KCAT;
    } else {
        At = Wcat + ((size_t)(512 + bym * 128)) * KCAT;
        Bt = xcat + ((size_t)(bxn * 128)) * KCAT;
    }
    const size_t lane_off = (size_t)lr * KCAT + gg * 8;

    floatx4 acc[4][4];
#pragma unroll
    for (int i = 0; i < 4; i++)
#pragma unroll
        for (int j = 0; j < 4; j++) acc[i][j] = (floatx4)0.0f;

    const int rowA = l & 15;
    const int sg0  = (l >> 4) ^ (l & 7);
    const int sg1  = sg0 ^ 4;

    for (int kc = 0; kc < KCAT; kc += 64) {
#pragma unroll
        for (int s = 0; s < 4; s++) {
            const int seg = wave * 4 + s;
            gload16(At + (size_t)seg * 8 * KCAT + lane_off + kc, &As[seg * 8][0]);
            gload16(Bt + (size_t)seg * 8 * KCAT + lane_off + kc, &Bs[seg * 8][0]);
        }
        __syncthreads();
#pragma unroll
        for (int ks = 0; ks < 2; ks++) {
            const int sg = ks ? sg1 : sg0;
            half8 af[4], bf[4];
#pragma unroll
            for (int mi = 0; mi < 4; mi++)
                af[mi] = *(const half8*)&As[wr * 64 + mi * 16 + rowA][sg * 8];
#pragma unroll
            for (int ni = 0; ni < 4; ni++)
                bf[ni] = *(const half8*)&Bs[wc * 64 + ni * 16 + rowA][sg * 8];
#pragma unroll
            for (int mi = 0; mi < 4; mi++)
#pragma unroll
                for (int ni = 0; ni < 4; ni++)
                    acc[mi][ni] = __builtin_amdgcn_mfma_f32_16x16x32_f16(
                        af[mi], bf[ni], acc[mi][ni], 0, 0, 0);
        }
        __syncthreads();
    }

    if (mat < 2) {
        const float* bias = (mat == 0) ? bq : bk;
        _Float16* Out = (mat == 0) ? Qcat : Kcat;
#pragma unroll
        for (int ni = 0; ni < 4; ni++) {
            int ch = bxn * 128 + wc * 64 + ni * 16 + (l & 15);
            float bb = bias[ch];
#pragma unroll
            for (int mi = 0; mi < 4; mi++)
#pragma unroll
                for (int rg = 0; rg < 4; rg++) {
                    int token = bym * 128 + wr * 64 + mi * 16 + (l >> 4) * 4 + rg;
                    float v = acc[mi][ni][rg] + bb;
                    _Float16 hi = (_Float16)v;
                    _Float16 lo = (_Float16)(v - (float)hi);
                    _Float16* p = Out + (size_t)token * KCAT + ch;
                    if (mat == 0) { p[0] = hi; p[256] = lo; p[512] = hi; }
                    else          { p[0] = hi; p[256] = hi; p[512] = lo; }
                }
        }
    } else {
#pragma unroll
        for (int mi = 0; mi < 4; mi++)
#pragma unroll
            for (int rg = 0; rg < 4; rg++) {
                int ch = bym * 128 + wr * 64 + mi * 16 + (l >> 4) * 4 + rg;
                float bb = bv[ch];
#pragma unroll
                for (int ni = 0; ni < 4; ni++) {
                    int col = bxn * 128 + wc * 64 + ni * 16 + (l & 15);
                    int b = col >> 12, n = col & 4095;
                    Vt[((size_t)((b << 8) + ch)) * NN + n] =
                        (_Float16)(acc[mi][ni][rg] + bb);
                }
            }
    }
}

// ---------- kernel 3: S = (Qcat @ Kcat^T) * SCALE via MFMA f16 ----------
// 256x256 block tile, 512 thr = 8 waves (4x2), async swizzled staging.
// XCD-aware 8x8 supercell decode: all 512 blocks co-resident (2/CU); with
// round-robin id%8 -> XCD placement each XCD touches only 8 A-strips + 8
// B-strips (6 MB) instead of ~25 MB -> L2-served re-reads.
__global__ __launch_bounds__(512, 2) void score_gemm(
        const _Float16* __restrict__ Qcat, const _Float16* __restrict__ Kcat,
        float* __restrict__ S) {
    __shared__ _Float16 As[256][64];
    __shared__ _Float16 Bs[256][64];

    const int t    = threadIdx.x;
    const int wave = t >> 6;             // 0..7
    const int l    = t & 63;
    const int wr   = wave >> 1;          // 0..3 (M)
    const int wc   = wave & 1;           // 0..1 (N)

    const int id  = blockIdx.x;
    const int sc  = id & 7;              // supercell == XCD (id%8 round-robin)
    const int j   = id >> 3;             // 0..63 within supercell
    const int b   = sc & 1;
    const int scq = sc >> 1;             // quadrant 0..3
    const int bxn = ((scq & 1) << 3) + (j & 7);
    const int bym = ((scq >> 1) << 3) + (j >> 3);

    const int lr = l >> 3;
    const int gg = (l & 7) ^ lr;

    const _Float16* At = Qcat + ((size_t)((b << 12) + bym * 256)) * KCAT;
    const _Float16* Bt = Kcat + ((size_t)((b << 12) + bxn * 256)) * KCAT;
    const size_t lane_off = (size_t)lr * KCAT + gg * 8;

    floatx4 acc[4][8];
#pragma unroll
    for (int i = 0; i < 4; i++)
#pragma unroll
        for (int jj = 0; jj < 8; jj++) acc[i][jj] = (floatx4)0.0f;

    const int rowA = l & 15;
    const int sg0  = (l >> 4) ^ (l & 7);
    const int sg1  = sg0 ^ 4;

    for (int kc = 0; kc < KCAT; kc += 64) {
#pragma unroll
        for (int s = 0; s < 4; s++) {
            const int seg = wave * 4 + s;
            gload16(At + (size_t)seg * 8 * KCAT + lane_off + kc, &As[seg * 8][0]);
            gload16(Bt + (size_t)seg * 8 * KCAT + lane_off + kc, &Bs[seg * 8][0]);
        }
        __syncthreads();
#pragma unroll
        for (int ks = 0; ks < 2; ks++) {
            const int sg = ks ? sg1 : sg0;
            half8 af[4], bf[8];
#pragma unroll
            for (int mi = 0; mi < 4; mi++)
                af[mi] = *(const half8*)&As[wr * 64 + mi * 16 + rowA][sg * 8];
#pragma unroll
            for (int ni = 0; ni < 8; ni++)
                bf[ni] = *(const half8*)&Bs[wc * 128 + ni * 16 + rowA][sg * 8];
#pragma unroll
            for (int mi = 0; mi < 4; mi++)
#pragma unroll
                for (int ni = 0; ni < 8; ni++)
                    acc[mi][ni] = __builtin_amdgcn_mfma_f32_16x16x32_f16(
                        af[mi], bf[ni], acc[mi][ni], 0, 0, 0);
        }
        __syncthreads();
    }

    float* Sb = S + ((size_t)b << 24);
#pragma unroll
    for (int mi = 0; mi < 4; mi++)
#pragma unroll
        for (int ni = 0; ni < 8; ni++) {
            int col = bxn * 256 + wc * 128 + ni * 16 + (l & 15);
#pragma unroll
            for (int rg = 0; rg < 4; rg++) {
                int row = bym * 256 + wr * 64 + mi * 16 + (l >> 4) * 4 + rg;
                Sb[((size_t)row << 12) + col] = acc[mi][ni][rg] * SCALE;
            }
        }
}

// ---------- kernel 4: per-row exact top-k + softmax -> dense fp16 P row ----------
__global__ __launch_bounds__(256) void select_scatter(
        const float* __restrict__ S, _Float16* __restrict__ P) {
    __shared__ unsigned hist[256];
    __shared__ unsigned scan[256];
    __shared__ unsigned candKey[NN];     // worst case: all in one bin
    __shared__ unsigned wred[4];
    __shared__ float    fmn[4], fmx[4], wsum[4];
    __shared__ unsigned sh_d, sh_cntgt, sh_T;
    __shared__ int      sh_ncand, sh_need;

    const int t = threadIdx.x;
    const int l = t & 63;
    const int w = t >> 6;

    float    val[16];
    unsigned ukey[16];
    {
        const float*  Srow = S + ((size_t)blockIdx.x << 12);
        const float4* sp   = (const float4*)(Srow + t * 16);
#pragma unroll
        for (int jj = 0; jj < 4; jj++) {
            float4 v = sp[jj];
            val[jj * 4 + 0] = v.x; val[jj * 4 + 1] = v.y;
            val[jj * 4 + 2] = v.z; val[jj * 4 + 3] = v.w;
        }
#pragma unroll
        for (int j = 0; j < 16; j++) ukey[j] = fkey(val[j]);
    }

    // row min/max via wave reduce
    float lmin = val[0], lmax = val[0];
#pragma unroll
    for (int j = 1; j < 16; j++) {
        lmin = fminf(lmin, val[j]); lmax = fmaxf(lmax, val[j]);
    }
#pragma unroll
    for (int off = 32; off > 0; off >>= 1) {
        float a = __shfl_down(lmin, off);
        float b = __shfl_down(lmax, off);
        if (l + off < 64) { lmin = fminf(lmin, a); lmax = fmaxf(lmax, b); }
    }
    if (l == 0) { fmn[w] = lmin; fmx[w] = lmax; }

    hist[t] = 0u;
    if (t == 0) sh_ncand = 0;
    __syncthreads();
    const float fmin = fminf(fminf(fmn[0], fmn[1]), fminf(fmn[2], fmn[3]));
    const float fmax = fmaxf(fmaxf(fmx[0], fmx[1]), fmaxf(fmx[2], fmx[3]));
    const float range = fmax - fmin;
    const float bscale = (range > 1e-20f) ? 255.0f / range : 0.0f;

    auto binOf = [&](float v) -> int {
        int bin = (int)((v - fmin) * bscale);
        return bin < 0 ? 0 : (bin > 255 ? 255 : bin);
    };

    // ---- level 1: linear histogram ----
#pragma unroll
    for (int j = 0; j < 16; j++) atomicAdd(&hist[binOf(val[j])], 1u);
    __syncthreads();

    int rem = KK;

    auto find_digit = [&](int remv) {
        unsigned v = hist[t];
#pragma unroll
        for (int off = 1; off < 64; off <<= 1) {
            unsigned o = __shfl_down(v, off);
            if (l + off < 64) v += o;
        }
        if (l == 0) wred[w] = v;
        __syncthreads();
        unsigned add = 0u;
#pragma unroll
        for (int w2 = 0; w2 < 4; w2++) if (w2 > w) add += wred[w2];
        scan[t] = v + add;
        __syncthreads();
        unsigned sufd  = scan[t];
        unsigned sufd1 = (t < 255) ? scan[t + 1] : 0u;
        if (sufd >= (unsigned)remv && sufd1 < (unsigned)remv) {
            sh_d = (unsigned)t; sh_cntgt = sufd1;
        }
        __syncthreads();
    };

    find_digit(rem);
    const int dbin = (int)sh_d;
    rem -= (int)sh_cntgt;

    // compact threshold-bin candidates (expected ~tens)
#pragma unroll
    for (int j = 0; j < 16; j++) {
        if (binOf(val[j]) == dbin) {
            int slot = atomicAdd(&sh_ncand, 1);
            candKey[slot] = ukey[j];
        }
    }
    __syncthreads();
    const int nc = sh_ncand;

    // ---- level 2: exact rem-th largest among candidates ----
    if (nc <= 64) {
        if (w == 0) {
            unsigned kl = (l < nc) ? candKey[l] : 0u;  // 0 = -inf key
            int r = 0, g = 0;
            for (int j = 0; j < 64; j++) {
                unsigned kj = __shfl(kl, j);
                bool gt = kj > kl;
                g += gt ? 1 : 0;
                r += (gt || (kj == kl && j < l)) ? 1 : 0;  // stable rank
            }
            if (r == rem - 1) { sh_T = kl; sh_need = rem - g; }
        }
    } else {
        unsigned prefix = 0u;
        int rem2 = rem;
        for (int pass = 0; pass < 4; pass++) {
            const int shift = 24 - 8 * pass;
            hist[t] = 0u;
            __syncthreads();
            for (int i = t; i < nc; i += 256) {
                unsigned u2 = candKey[i];
                if (pass == 0 || (u2 >> (shift + 8)) == (prefix >> (shift + 8)))
                    atomicAdd(&hist[(u2 >> shift) & 255u], 1u);
            }
            __syncthreads();
            find_digit(rem2);
            prefix |= (sh_d << shift);
            rem2 -= (int)sh_cntgt;
        }
        if (t == 0) { sh_T = prefix; sh_need = rem2; }
    }
    __syncthreads();
    const unsigned T = sh_T;
    const int need = sh_need;
    const float mT = keyToF(T);   // softmax shift: shift-invariant, any m works

    // stable tie-break: exclusive prefix of per-thread equal counts (wave scan)
    int eqc = 0;
#pragma unroll
    for (int j = 0; j < 16; j++) if (ukey[j] == T) eqc++;
    int vinc = eqc;
#pragma unroll
    for (int off = 1; off < 64; off <<= 1) {
        int o = __shfl_up(vinc, off);
        if (l >= off) vinc += o;
    }
    if (l == 63) wred[w] = (unsigned)vinc;
    __syncthreads();
    int addlow = 0;
#pragma unroll
    for (int w2 = 0; w2 < 4; w2++) if (w2 < w) addlow += (int)wred[w2];
    const int eqexcl = vinc - eqc + addlow;

    // selection + exp: u>T unconditional, ties = exp(0) = 1.0f exactly
    float pv[16];
    float le = 0.f;
#pragma unroll
    for (int j = 0; j < 16; j++) {
        float e = 0.f;
        if (ukey[j] > T) { e = __expf(val[j] - mT); le += e; }
        pv[j] = e;
    }
    if (eqc) {
        int seen = 0;
#pragma unroll
        for (int j = 0; j < 16; j++) {
            if (ukey[j] == T) {
                if (eqexcl + seen < need) { pv[j] = 1.0f; le += 1.0f; }
                seen++;
            }
        }
    }

    // sum reduce
#pragma unroll
    for (int off = 32; off > 0; off >>= 1) {
        float o = __shfl_down(le, off);
        if (l + off < 64) le += o;
    }
    if (l == 0) wsum[w] = le;
    __syncthreads();
    const float inv = 1.0f / (wsum[0] + wsum[1] + wsum[2] + wsum[3]);

    half8 ra, rb;
#pragma unroll
    for (int j = 0; j < 8; j++) {
        ra[j] = (_Float16)(pv[j] * inv);
        rb[j] = (_Float16)(pv[j + 8] * inv);
    }
    _Float16* Pr = P + (size_t)blockIdx.x * PSTRIDE + t * 16;
    *(half8*)Pr       = ra;
    *(half8*)(Pr + 8) = rb;
}

// ---------- kernel 5: out[b][c][n] = sum_m Vt[c][m] * P[n][m] via MFMA f16 ----------
__global__ __launch_bounds__(256) void av_gemm(
        const _Float16* __restrict__ Vt, const _Float16* __restrict__ P,
        float* __restrict__ out) {
    __shared__ _Float16 As0[64][64], As1[64][64];
    __shared__ _Float16 Bs0[64][64], Bs1[64][64];

    const int t    = threadIdx.x;
    const int wave = t >> 6;
    const int l    = t & 63;
    const int wr   = wave >> 1;
    const int wc   = wave & 1;
    const int bxn  = blockIdx.x;
    const int byc  = blockIdx.y;
    const int b    = blockIdx.z;

    const int lr = l >> 3;
    const int gg = (l & 7) ^ lr;

    const _Float16* At = Vt + ((size_t)((b << 8) + byc * 64)) * NN;
    const _Float16* Bt = P + ((size_t)(b * NN + bxn * 64)) * PSTRIDE;
    const size_t lane_offA = (size_t)lr * NN + gg * 8;
    const size_t lane_offB = (size_t)lr * PSTRIDE + gg * 8;

    floatx4 acc[2][2];
#pragma unroll
    for (int i = 0; i < 2; i++)
#pragma unroll
        for (int j = 0; j < 2; j++) acc[i][j] = (floatx4)0.0f;

    const int rowA   = l & 15;
    const int sgbase = (l >> 4) ^ (l & 7);

    for (int kc = 0; kc < NN; kc += 128) {
#pragma unroll
        for (int s = 0; s < 2; s++) {
            const int seg = wave * 2 + s;
            gload16(At + (size_t)seg * 8 * NN + lane_offA + kc,           &As0[seg * 8][0]);
            gload16(At + (size_t)seg * 8 * NN + lane_offA + kc + 64,      &As1[seg * 8][0]);
            gload16(Bt + (size_t)seg * 8 * PSTRIDE + lane_offB + kc,      &Bs0[seg * 8][0]);
            gload16(Bt + (size_t)seg * 8 * PSTRIDE + lane_offB + kc + 64, &Bs1[seg * 8][0]);
        }
        __syncthreads();
#pragma unroll
        for (int st = 0; st < 4; st++) {
            const _Float16 (*Ap)[64] = (st < 2) ? As0 : As1;
            const _Float16 (*Bp)[64] = (st < 2) ? Bs0 : Bs1;
            const int sg = sgbase ^ ((st & 1) ? 4 : 0);
            half8 af[2], bf[2];
#pragma unroll
            for (int mi = 0; mi < 2; mi++)
                af[mi] = *(const half8*)&Ap[wr * 32 + mi * 16 + rowA][sg * 8];
#pragma unroll
            for (int ni = 0; ni < 2; ni++)
                bf[ni] = *(const half8*)&Bp[wc * 32 + ni * 16 + rowA][sg * 8];
#pragma unroll
            for (int mi = 0; mi < 2; mi++)
#pragma unroll
                for (int ni = 0; ni < 2; ni++)
                    acc[mi][ni] = __builtin_amdgcn_mfma_f32_16x16x32_f16(
                        af[mi], bf[ni], acc[mi][ni], 0, 0, 0);
        }
        __syncthreads();
    }

#pragma unroll
    for (int mi = 0; mi < 2; mi++)
#pragma unroll
        for (int ni = 0; ni < 2; ni++) {
            int col = bxn * 64 + wc * 32 + ni * 16 + (l & 15);
#pragma unroll
            for (int rg = 0; rg < 4; rg++) {
                int row = byc * 64 + wr * 32 + mi * 16 + (l >> 4) * 4 + rg;
                out[((size_t)((b << 8) + row) << 12) + col] = acc[mi][ni][rg];
            }
        }
}

extern "C" void kernel_launch(void* const* d_in, const int* in_sizes, int n_in,
                              void* d_out, int out_size, void* d_ws, size_t ws_size,
                              hipStream_t stream) {
    const float* x  = (const float*)d_in[0];
    const float* Wq = (const float*)d_in[1];
    const float* bq = (const float*)d_in[2];
    const float* Wk = (const float*)d_in[3];
    const float* bk = (const float*)d_in[4];
    const float* Wv = (const float*)d_in[5];
    const float* bv = (const float*)d_in[6];
    float* out = (float*)d_out;

    char* ws = (char*)d_ws;
    _Float16* Wcat = (_Float16*)ws;                            // 1.18 MB
    _Float16* Qcat = (_Float16*)(ws + 1179648);                // 12.6 MB
    _Float16* Kcat = (_Float16*)(ws + 1179648 + 12582912);     // 12.6 MB
    _Float16* Vt   = (_Float16*)(ws + 1179648 + 2 * 12582912); // 4 MB
    float*    S    = (float*)   (ws + 1179648 + 2 * 12582912 + 4194304); // 128 MB
    _Float16* xcat = (_Float16*)S;   // xcat dead before score_gemm writes S
    _Float16* P    = (_Float16*)S;   // P aliases S rows (proven safe)

    xpose_wcat_kernel<<<dim3(64, 5, BATCH), 256, 0, stream>>>(x, Wq, Wk, Wv,
                                                              xcat, Wcat);
    proj_gemm<<<dim3(128, 1, 3), 256, 0, stream>>>(xcat, Wcat, bq, bk, bv,
                                                   Qcat, Kcat, Vt);
    score_gemm<<<dim3(512, 1, 1), 512, 0, stream>>>(Qcat, Kcat, S);
    select_scatter<<<BATCH * NN, 256, 0, stream>>>(S, P);
    av_gemm<<<dim3(64, 4, BATCH), 256, 0, stream>>>(Vt, P, out);
}